// Round 1
// baseline (303.485 us; speedup 1.0000x reference)
//
#include <hip/hip_runtime.h>

#define B_ 16
#define N_ 1024
#define D_ 768
#define H_ 12
#define HD_ 64
// SCALE = 1/sqrt(64) = 0.125 exactly

typedef __attribute__((ext_vector_type(8))) __bf16 bf16x8;
typedef __attribute__((ext_vector_type(4))) float f32x4;

__device__ inline unsigned short f2bf(float f) {
    unsigned int u = __builtin_bit_cast(unsigned int, f);
    u += 0x7fffu + ((u >> 16) & 1u);   // round-to-nearest-even
    return (unsigned short)(u >> 16);
}

// ---------------- kernel 1: x fp32 -> bf16 -------------------------------
__global__ __launch_bounds__(256) void cvt_x_kernel(const float* __restrict__ x,
                                                    unsigned short* __restrict__ xbf) {
    int i = blockIdx.x * 256 + threadIdx.x;      // 8 elems per thread, exact cover
    const float4* p = (const float4*)x;
    float4 a = p[2 * i], b = p[2 * i + 1];
    union { unsigned short us[8]; int4 v; } u;
    u.us[0] = f2bf(a.x); u.us[1] = f2bf(a.y); u.us[2] = f2bf(a.z); u.us[3] = f2bf(a.w);
    u.us[4] = f2bf(b.x); u.us[5] = f2bf(b.y); u.us[6] = f2bf(b.z); u.us[7] = f2bf(b.w);
    ((int4*)xbf)[i] = u.v;
}

// ---------------- kernel 2: W [K][N] fp32 -> Wt [N][K] bf16 --------------
__global__ void wt_kernel(const float* __restrict__ Wq, const float* __restrict__ Wk,
                          const float* __restrict__ Wv,
                          unsigned short* __restrict__ wtq, unsigned short* __restrict__ wtk,
                          unsigned short* __restrict__ wtv) {
    const float* W = blockIdx.z == 0 ? Wq : (blockIdx.z == 1 ? Wk : Wv);
    unsigned short* Wt = blockIdx.z == 0 ? wtq : (blockIdx.z == 1 ? wtk : wtv);
    __shared__ unsigned short t[32][33];
    int n0 = blockIdx.x * 32, k0 = blockIdx.y * 32;
#pragma unroll
    for (int i = 0; i < 4; i++) {
        int k = k0 + threadIdx.y + i * 8;
        t[threadIdx.y + i * 8][threadIdx.x] = f2bf(W[k * D_ + n0 + threadIdx.x]);
    }
    __syncthreads();
#pragma unroll
    for (int i = 0; i < 4; i++) {
        int n = n0 + threadIdx.y + i * 8;
        Wt[n * D_ + k0 + threadIdx.x] = t[threadIdx.x][threadIdx.y + i * 8];
    }
}

// ---------------- kernel 3: QKV projection GEMM --------------------------
// Y = x @ W + b.  64x64 tile / block, 4 waves, each wave a 16x64 strip.
// mode 0/1 (q/k): write bf16 [B,H,N,HD].  mode 2 (v): write bf16 [B,H,HD,N].
__global__ __launch_bounds__(256) void qkv_gemm_kernel(
    const unsigned short* __restrict__ xbf,
    const unsigned short* __restrict__ wtq, const unsigned short* __restrict__ wtk,
    const unsigned short* __restrict__ wtv,
    const float* __restrict__ bq, const float* __restrict__ bk, const float* __restrict__ bv,
    unsigned short* __restrict__ qout, unsigned short* __restrict__ kout,
    unsigned short* __restrict__ vtout) {
    const int mt = blockIdx.x;         // 256 M-tiles
    const int nt = blockIdx.y;         // 12 N-tiles == head index
    const int mode = blockIdx.z;       // 0=q 1=k 2=v
    const unsigned short* wt = mode == 0 ? wtq : (mode == 1 ? wtk : wtv);
    const float* bias = mode == 0 ? bq : (mode == 1 ? bk : bv);

    __shared__ unsigned short lx[64][72];   // x tile  [m][k], +8 pad
    __shared__ unsigned short lw[64][72];   // Wt tile [n][k], +8 pad

    const int tid = threadIdx.x;
    const int w = tid >> 6, lane = tid & 63, g = lane >> 4, c = lane & 15;
    const int m0 = mt * 64, n0 = nt * 64;

    f32x4 acc[4];
#pragma unroll
    for (int i = 0; i < 4; i++) acc[i] = (f32x4){0.f, 0.f, 0.f, 0.f};

    for (int k0 = 0; k0 < D_; k0 += 64) {
#pragma unroll
        for (int it = 0; it < 2; ++it) {
            int ch = tid + it * 256;           // 512 chunks of 16B
            int row = ch >> 3, col8 = ch & 7;
            *(int4*)&lx[row][col8 * 8] = *(const int4*)&xbf[(m0 + row) * D_ + k0 + col8 * 8];
            *(int4*)&lw[row][col8 * 8] = *(const int4*)&wt[(n0 + row) * D_ + k0 + col8 * 8];
        }
        __syncthreads();
        bf16x8 a0 = *(const bf16x8*)&lx[w * 16 + c][g * 8];
        bf16x8 a1 = *(const bf16x8*)&lx[w * 16 + c][32 + g * 8];
#pragma unroll
        for (int nf = 0; nf < 4; nf++) {
            bf16x8 b0 = *(const bf16x8*)&lw[nf * 16 + c][g * 8];
            bf16x8 b1 = *(const bf16x8*)&lw[nf * 16 + c][32 + g * 8];
            acc[nf] = __builtin_amdgcn_mfma_f32_16x16x32_bf16(a0, b0, acc[nf], 0, 0, 0);
            acc[nf] = __builtin_amdgcn_mfma_f32_16x16x32_bf16(a1, b1, acc[nf], 0, 0, 0);
        }
        __syncthreads();
    }

    if (mode < 2) {
        unsigned short* outp = mode == 0 ? qout : kout;
#pragma unroll
        for (int nf = 0; nf < 4; nf++) {
            int hd = nf * 16 + c;
            float bb = bias[n0 + hd];
#pragma unroll
            for (int r = 0; r < 4; r++) {
                int m = m0 + w * 16 + g * 4 + r;
                int b = m >> 10, n = m & 1023;
                outp[((b * H_ + nt) * N_ + n) * HD_ + hd] = f2bf(acc[nf][r] + bb);
            }
        }
    } else {
        // stage [m][hd] then write transposed rows (hd-major) coalesced
#pragma unroll
        for (int nf = 0; nf < 4; nf++) {
            int hd = nf * 16 + c;
            float bb = bias[n0 + hd];
#pragma unroll
            for (int r = 0; r < 4; r++)
                lx[w * 16 + g * 4 + r][hd] = f2bf(acc[nf][r] + bb);
        }
        __syncthreads();
        int b = m0 >> 10, nb = m0 & 1023;
#pragma unroll
        for (int it = 0; it < 2; ++it) {
            int ch = tid + it * 256;
            int hdrow = ch >> 3, col8 = ch & 7;
            union { unsigned short us[8]; int4 v; } u;
#pragma unroll
            for (int j = 0; j < 8; j++) u.us[j] = lx[col8 * 8 + j][hdrow];
            *(int4*)&vtout[((b * H_ + nt) * HD_ + hdrow) * N_ + nb + col8 * 8] = u.v;
        }
    }
}

// ---------------- kernel 4: flash attention ------------------------------
// block = (q-tile of 64 rows) x (b,h).  4 waves, each 16 q rows.
__global__ __launch_bounds__(256) void attn_kernel(
    const unsigned short* __restrict__ qbf, const unsigned short* __restrict__ kbf,
    const unsigned short* __restrict__ vtbf, float* __restrict__ out) {
    __shared__ unsigned short lk[64][72];      // K tile  [kv][hd]
    __shared__ unsigned short lv[64][72];      // Vt tile [hd][kv]
    __shared__ unsigned short lp[4][16][72];   // P per wave [q][kv]

    const int qt = blockIdx.x;       // 16 q-tiles
    const int bh = blockIdx.y;       // 192
    const int b = bh / H_, h = bh % H_;
    const int tid = threadIdx.x;
    const int w = tid >> 6, lane = tid & 63, g = lane >> 4, c = lane & 15;
    const int q0 = qt * 64;

    const unsigned short* qrow = qbf + ((size_t)bh * N_ + q0 + w * 16 + c) * HD_;
    bf16x8 aq0 = *(const bf16x8*)&qrow[g * 8];
    bf16x8 aq1 = *(const bf16x8*)&qrow[32 + g * 8];

    f32x4 o[4];
#pragma unroll
    for (int i = 0; i < 4; i++) o[i] = (f32x4){0.f, 0.f, 0.f, 0.f};
    float mr[4] = {-1e30f, -1e30f, -1e30f, -1e30f};
    float lr[4] = {0.f, 0.f, 0.f, 0.f};

    for (int kv0 = 0; kv0 < N_; kv0 += 64) {
#pragma unroll
        for (int it = 0; it < 2; ++it) {
            int ch = tid + it * 256;
            int row = ch >> 3, col8 = ch & 7;
            *(int4*)&lk[row][col8 * 8] =
                *(const int4*)&kbf[((size_t)bh * N_ + kv0 + row) * HD_ + col8 * 8];
            *(int4*)&lv[row][col8 * 8] =
                *(const int4*)&vtbf[((size_t)bh * HD_ + row) * N_ + kv0 + col8 * 8];
        }
        __syncthreads();

        // S = Q K^T : A=Q frag, B=K^T frag (contiguous reads of lk rows)
        f32x4 s[4];
#pragma unroll
        for (int i = 0; i < 4; i++) s[i] = (f32x4){0.f, 0.f, 0.f, 0.f};
#pragma unroll
        for (int nf = 0; nf < 4; nf++) {
            bf16x8 bk0 = *(const bf16x8*)&lk[nf * 16 + c][g * 8];
            bf16x8 bk1 = *(const bf16x8*)&lk[nf * 16 + c][32 + g * 8];
            s[nf] = __builtin_amdgcn_mfma_f32_16x16x32_bf16(aq0, bk0, s[nf], 0, 0, 0);
            s[nf] = __builtin_amdgcn_mfma_f32_16x16x32_bf16(aq1, bk1, s[nf], 0, 0, 0);
        }
#pragma unroll
        for (int nf = 0; nf < 4; nf++) s[nf] *= 0.125f;   // * HD^-0.5

        // online softmax; row = g*4+r, cols spread over nf (in-lane) and c (x-lane)
        float alpha[4], rs[4];
#pragma unroll
        for (int r = 0; r < 4; r++) {
            float mx = fmaxf(fmaxf(s[0][r], s[1][r]), fmaxf(s[2][r], s[3][r]));
            mx = fmaxf(mx, __shfl_xor(mx, 1));
            mx = fmaxf(mx, __shfl_xor(mx, 2));
            mx = fmaxf(mx, __shfl_xor(mx, 4));
            mx = fmaxf(mx, __shfl_xor(mx, 8));
            float mn = fmaxf(mr[r], mx);
            alpha[r] = __expf(mr[r] - mn);
            mr[r] = mn;
            rs[r] = 0.f;
        }
#pragma unroll
        for (int nf = 0; nf < 4; nf++)
#pragma unroll
            for (int r = 0; r < 4; r++) {
                float p = __expf(s[nf][r] - mr[r]);
                s[nf][r] = p;
                rs[r] += p;
            }
#pragma unroll
        for (int r = 0; r < 4; r++) {
            rs[r] += __shfl_xor(rs[r], 1);
            rs[r] += __shfl_xor(rs[r], 2);
            rs[r] += __shfl_xor(rs[r], 4);
            rs[r] += __shfl_xor(rs[r], 8);
            lr[r] = lr[r] * alpha[r] + rs[r];
        }
#pragma unroll
        for (int nf = 0; nf < 4; nf++)
#pragma unroll
            for (int r = 0; r < 4; r++) o[nf][r] *= alpha[r];

        // P -> LDS (bf16), re-fragment as A for PV
#pragma unroll
        for (int nf = 0; nf < 4; nf++)
#pragma unroll
            for (int r = 0; r < 4; r++) lp[w][g * 4 + r][nf * 16 + c] = f2bf(s[nf][r]);
        __syncthreads();   // also orders ushort stores vs bf16x8 loads

        bf16x8 pa0 = *(const bf16x8*)&lp[w][c][g * 8];
        bf16x8 pa1 = *(const bf16x8*)&lp[w][c][32 + g * 8];
#pragma unroll
        for (int nf = 0; nf < 4; nf++) {
            bf16x8 bv0 = *(const bf16x8*)&lv[nf * 16 + c][g * 8];
            bf16x8 bv1 = *(const bf16x8*)&lv[nf * 16 + c][32 + g * 8];
            o[nf] = __builtin_amdgcn_mfma_f32_16x16x32_bf16(pa0, bv0, o[nf], 0, 0, 0);
            o[nf] = __builtin_amdgcn_mfma_f32_16x16x32_bf16(pa1, bv1, o[nf], 0, 0, 0);
        }
        __syncthreads();
    }

    // out[b, n, h*64+hd] = o / l
#pragma unroll
    for (int r = 0; r < 4; r++) {
        float inv = 1.f / lr[r];
        int n = q0 + w * 16 + g * 4 + r;
#pragma unroll
        for (int nf = 0; nf < 4; nf++)
            out[((size_t)(b * N_ + n)) * D_ + h * HD_ + nf * 16 + c] = o[nf][r] * inv;
    }
}

// ---------------- launcher ----------------------------------------------
extern "C" void kernel_launch(void* const* d_in, const int* in_sizes, int n_in,
                              void* d_out, int out_size, void* d_ws, size_t ws_size,
                              hipStream_t stream) {
    const float* x  = (const float*)d_in[0];
    const float* Wq = (const float*)d_in[1];
    const float* bq = (const float*)d_in[2];
    const float* Wk = (const float*)d_in[3];
    const float* bk = (const float*)d_in[4];
    const float* Wv = (const float*)d_in[5];
    const float* bv = (const float*)d_in[6];
    float* out = (float*)d_out;

    char* ws = (char*)d_ws;
    unsigned short* xbf  = (unsigned short*)ws;                    // 16384*768*2 = 25165824
    unsigned short* wtq  = (unsigned short*)(ws + 25165824);       // 768*768*2 each
    unsigned short* wtk  = wtq + D_ * D_;
    unsigned short* wtv  = wtk + D_ * D_;
    unsigned short* qbf  = (unsigned short*)(ws + 28704768);       // [B,H,N,64] bf16
    unsigned short* kbf  = qbf + (size_t)B_ * H_ * N_ * HD_;
    unsigned short* vtbf = kbf + (size_t)B_ * H_ * N_ * HD_;       // [B,H,64,N] bf16

    cvt_x_kernel<<<6144, 256, 0, stream>>>(x, xbf);
    dim3 gw(24, 24, 3), bw(32, 8);
    wt_kernel<<<gw, bw, 0, stream>>>(Wq, Wk, Wv, wtq, wtk, wtv);
    dim3 gg(256, 12, 3);
    qkv_gemm_kernel<<<gg, 256, 0, stream>>>(xbf, wtq, wtk, wtv, bq, bk, bv, qbf, kbf, vtbf);
    dim3 ga(16, 192);
    attn_kernel<<<ga, 256, 0, stream>>>(qbf, kbf, vtbf, out);
}

// Round 2
// 252.984 us; speedup vs baseline: 1.1996x; 1.1996x over previous
//
#include <hip/hip_runtime.h>

#define B_ 16
#define N_ 1024
#define D_ 768
#define H_ 12
#define HD_ 64
// Q is pre-scaled by 0.125 * log2(e) so softmax is exp2-based.
#define QSCALE 0.18033688011112042f

typedef __attribute__((ext_vector_type(8))) __bf16 bf16x8;
typedef __attribute__((ext_vector_type(4))) float f32x4;

__device__ inline unsigned short f2bf(float f) {
    unsigned int u = __builtin_bit_cast(unsigned int, f);
    u += 0x7fffu + ((u >> 16) & 1u);   // round-to-nearest-even
    return (unsigned short)(u >> 16);
}

__device__ inline float fexp2(float x) {
#if __has_builtin(__builtin_amdgcn_exp2f)
    return __builtin_amdgcn_exp2f(x);
#else
    return exp2f(x);
#endif
}

// pack two f32 -> two bf16 in one u32 (lo = a, hi = b)
__device__ inline unsigned int cvt_pk_bf16(float a, float b) {
    unsigned int r;
    asm("v_cvt_pk_bf16_f32 %0, %1, %2" : "=v"(r) : "v"(a), "v"(b));
    return r;
}

// ---------------- kernel 1: x fp32 -> bf16 -------------------------------
__global__ __launch_bounds__(256) void cvt_x_kernel(const float* __restrict__ x,
                                                    unsigned short* __restrict__ xbf) {
    int i = blockIdx.x * 256 + threadIdx.x;      // 8 elems per thread, exact cover
    const float4* p = (const float4*)x;
    float4 a = p[2 * i], b = p[2 * i + 1];
    union { unsigned short us[8]; int4 v; } u;
    u.us[0] = f2bf(a.x); u.us[1] = f2bf(a.y); u.us[2] = f2bf(a.z); u.us[3] = f2bf(a.w);
    u.us[4] = f2bf(b.x); u.us[5] = f2bf(b.y); u.us[6] = f2bf(b.z); u.us[7] = f2bf(b.w);
    ((int4*)xbf)[i] = u.v;
}

// ---------------- kernel 2: W [K][N] fp32 -> Wt [N][K] bf16 --------------
__global__ void wt_kernel(const float* __restrict__ Wq, const float* __restrict__ Wk,
                          const float* __restrict__ Wv,
                          unsigned short* __restrict__ wtq, unsigned short* __restrict__ wtk,
                          unsigned short* __restrict__ wtv) {
    const float* W = blockIdx.z == 0 ? Wq : (blockIdx.z == 1 ? Wk : Wv);
    unsigned short* Wt = blockIdx.z == 0 ? wtq : (blockIdx.z == 1 ? wtk : wtv);
    __shared__ unsigned short t[32][33];
    int n0 = blockIdx.x * 32, k0 = blockIdx.y * 32;
#pragma unroll
    for (int i = 0; i < 4; i++) {
        int k = k0 + threadIdx.y + i * 8;
        t[threadIdx.y + i * 8][threadIdx.x] = f2bf(W[k * D_ + n0 + threadIdx.x]);
    }
    __syncthreads();
#pragma unroll
    for (int i = 0; i < 4; i++) {
        int n = n0 + threadIdx.y + i * 8;
        Wt[n * D_ + k0 + threadIdx.x] = t[threadIdx.x][threadIdx.y + i * 8];
    }
}

// ---------------- kernel 3: QKV projection GEMM --------------------------
// Y = x @ W + b.  64x64 tile / block, 4 waves, each wave a 16x64 strip.
// mode 0/1 (q/k): write bf16 [B,H,N,HD] (q additionally scaled by QSCALE).
// mode 2 (v): write bf16 [B,H,HD,N].
__global__ __launch_bounds__(256) void qkv_gemm_kernel(
    const unsigned short* __restrict__ xbf,
    const unsigned short* __restrict__ wtq, const unsigned short* __restrict__ wtk,
    const unsigned short* __restrict__ wtv,
    const float* __restrict__ bq, const float* __restrict__ bk, const float* __restrict__ bv,
    unsigned short* __restrict__ qout, unsigned short* __restrict__ kout,
    unsigned short* __restrict__ vtout) {
    const int mt = blockIdx.x;         // 256 M-tiles
    const int nt = blockIdx.y;         // 12 N-tiles == head index
    const int mode = blockIdx.z;       // 0=q 1=k 2=v
    const unsigned short* wt = mode == 0 ? wtq : (mode == 1 ? wtk : wtv);
    const float* bias = mode == 0 ? bq : (mode == 1 ? bk : bv);
    const float osc = mode == 0 ? QSCALE : 1.0f;

    __shared__ unsigned short lx[64][72];   // x tile  [m][k], +8 pad
    __shared__ unsigned short lw[64][72];   // Wt tile [n][k], +8 pad

    const int tid = threadIdx.x;
    const int w = tid >> 6, lane = tid & 63, g = lane >> 4, c = lane & 15;
    const int m0 = mt * 64, n0 = nt * 64;

    f32x4 acc[4];
#pragma unroll
    for (int i = 0; i < 4; i++) acc[i] = (f32x4){0.f, 0.f, 0.f, 0.f};

    for (int k0 = 0; k0 < D_; k0 += 64) {
#pragma unroll
        for (int it = 0; it < 2; ++it) {
            int ch = tid + it * 256;           // 512 chunks of 16B
            int row = ch >> 3, col8 = ch & 7;
            *(int4*)&lx[row][col8 * 8] = *(const int4*)&xbf[(m0 + row) * D_ + k0 + col8 * 8];
            *(int4*)&lw[row][col8 * 8] = *(const int4*)&wt[(n0 + row) * D_ + k0 + col8 * 8];
        }
        __syncthreads();
        bf16x8 a0 = *(const bf16x8*)&lx[w * 16 + c][g * 8];
        bf16x8 a1 = *(const bf16x8*)&lx[w * 16 + c][32 + g * 8];
#pragma unroll
        for (int nf = 0; nf < 4; nf++) {
            bf16x8 b0 = *(const bf16x8*)&lw[nf * 16 + c][g * 8];
            bf16x8 b1 = *(const bf16x8*)&lw[nf * 16 + c][32 + g * 8];
            acc[nf] = __builtin_amdgcn_mfma_f32_16x16x32_bf16(a0, b0, acc[nf], 0, 0, 0);
            acc[nf] = __builtin_amdgcn_mfma_f32_16x16x32_bf16(a1, b1, acc[nf], 0, 0, 0);
        }
        __syncthreads();
    }

    if (mode < 2) {
        unsigned short* outp = mode == 0 ? qout : kout;
#pragma unroll
        for (int nf = 0; nf < 4; nf++) {
            int hd = nf * 16 + c;
            float bb = bias[n0 + hd];
#pragma unroll
            for (int r = 0; r < 4; r++) {
                int m = m0 + w * 16 + g * 4 + r;
                int b = m >> 10, n = m & 1023;
                outp[((b * H_ + nt) * N_ + n) * HD_ + hd] = f2bf((acc[nf][r] + bb) * osc);
            }
        }
    } else {
        // stage [m][hd] then write transposed rows (hd-major) coalesced
#pragma unroll
        for (int nf = 0; nf < 4; nf++) {
            int hd = nf * 16 + c;
            float bb = bias[n0 + hd];
#pragma unroll
            for (int r = 0; r < 4; r++)
                lx[w * 16 + g * 4 + r][hd] = f2bf(acc[nf][r] + bb);
        }
        __syncthreads();
        int b = m0 >> 10, nb = m0 & 1023;
#pragma unroll
        for (int it = 0; it < 2; ++it) {
            int ch = tid + it * 256;
            int hdrow = ch >> 3, col8 = ch & 7;
            union { unsigned short us[8]; int4 v; } u;
#pragma unroll
            for (int j = 0; j < 8; j++) u.us[j] = lx[col8 * 8 + j][hdrow];
            *(int4*)&vtout[((b * H_ + nt) * HD_ + hdrow) * N_ + nb + col8 * 8] = u.v;
        }
    }
}

// ---------------- kernel 4: flash attention (swapped QK^T) ---------------
// block = (q-tile of 64 rows) x (b,h).  4 waves, each 16 q rows.
// S^T = mfma(A=K, B=Q): lane holds q = w*16 + (lane&15), kv = nf*16+g*4+r —
// a full row slice in-lane, so the softmax reduce is an in-lane tree + 2 shfl.
__global__ __launch_bounds__(256) void attn_kernel(
    const unsigned short* __restrict__ qbf, const unsigned short* __restrict__ kbf,
    const unsigned short* __restrict__ vtbf, float* __restrict__ out) {
    __shared__ unsigned short lk[64][72];      // K tile  [kv][hd]
    __shared__ unsigned short lv[64][72];      // Vt tile [hd][kv]
    __shared__ unsigned short lp[4][16][72];   // P per wave [q][kv]

    const int qt = blockIdx.x;       // 16 q-tiles
    const int bh = blockIdx.y;       // 192
    const int b = bh / H_, h = bh % H_;
    const int tid = threadIdx.x;
    const int w = tid >> 6, lane = tid & 63, g = lane >> 4, c = lane & 15;
    const int q0 = qt * 64;

    // Q fragment (B-operand): col = q = w*16+c, k = hd = g*8+j
    const unsigned short* qrow = qbf + ((size_t)bh * N_ + q0 + w * 16 + c) * HD_;
    bf16x8 aq0 = *(const bf16x8*)&qrow[g * 8];
    bf16x8 aq1 = *(const bf16x8*)&qrow[32 + g * 8];

    f32x4 o[4];
#pragma unroll
    for (int i = 0; i < 4; i++) o[i] = (f32x4){0.f, 0.f, 0.f, 0.f};
    float mr = -3e38f, lr = 0.f;     // running stats for q = w*16+c (scalar!)

    for (int kv0 = 0; kv0 < N_; kv0 += 64) {
#pragma unroll
        for (int it = 0; it < 2; ++it) {
            int ch = tid + it * 256;
            int row = ch >> 3, col8 = ch & 7;
            *(int4*)&lk[row][col8 * 8] =
                *(const int4*)&kbf[((size_t)bh * N_ + kv0 + row) * HD_ + col8 * 8];
            *(int4*)&lv[row][col8 * 8] =
                *(const int4*)&vtbf[((size_t)bh * HD_ + row) * N_ + kv0 + col8 * 8];
        }
        __syncthreads();

        // S^T = K Q^T : A=K rows (kv), B=Q cols (q). s[nf]: kv = nf*16+g*4+r, q = w*16+c
        f32x4 s[4];
#pragma unroll
        for (int i = 0; i < 4; i++) s[i] = (f32x4){0.f, 0.f, 0.f, 0.f};
#pragma unroll
        for (int nf = 0; nf < 4; nf++) {
            bf16x8 ak0 = *(const bf16x8*)&lk[nf * 16 + c][g * 8];
            bf16x8 ak1 = *(const bf16x8*)&lk[nf * 16 + c][32 + g * 8];
            s[nf] = __builtin_amdgcn_mfma_f32_16x16x32_bf16(ak0, aq0, s[nf], 0, 0, 0);
            s[nf] = __builtin_amdgcn_mfma_f32_16x16x32_bf16(ak1, aq1, s[nf], 0, 0, 0);
        }

        // row max for q=w*16+c: in-lane tree over 16 + xor16/32 across g-groups
        f32x4 m4 = s[0];
#pragma unroll
        for (int nf = 1; nf < 4; nf++) {
            m4[0] = fmaxf(m4[0], s[nf][0]); m4[1] = fmaxf(m4[1], s[nf][1]);
            m4[2] = fmaxf(m4[2], s[nf][2]); m4[3] = fmaxf(m4[3], s[nf][3]);
        }
        float mx = fmaxf(fmaxf(m4[0], m4[1]), fmaxf(m4[2], m4[3]));
        mx = fmaxf(mx, __shfl_xor(mx, 16));
        mx = fmaxf(mx, __shfl_xor(mx, 32));
        float mn = fmaxf(mr, mx);
        float alpha = fexp2(mr - mn);
        mr = mn;

        // P = exp2(S - m); row-sum
        f32x4 rsv = (f32x4){0.f, 0.f, 0.f, 0.f};
#pragma unroll
        for (int nf = 0; nf < 4; nf++) {
#pragma unroll
            for (int r = 0; r < 4; r++) s[nf][r] = fexp2(s[nf][r] - mr);
            rsv += s[nf];
        }
        float rs = (rsv[0] + rsv[1]) + (rsv[2] + rsv[3]);
        rs += __shfl_xor(rs, 16);
        rs += __shfl_xor(rs, 32);
        lr = lr * alpha + rs;

        // P^T -> lp[w][q][kv] packed bf16 (kv = nf*16+g*4 + 0..3 contiguous)
#pragma unroll
        for (int nf = 0; nf < 4; nf++) {
            union { unsigned int ui[2]; int2 v; } u;
            u.ui[0] = cvt_pk_bf16(s[nf][0], s[nf][1]);
            u.ui[1] = cvt_pk_bf16(s[nf][2], s[nf][3]);
            *(int2*)&lp[w][c][nf * 16 + g * 4] = u.v;
        }

        // broadcast alpha from stat-lanes (q=c') to O-fragment rows (q=g*4+r)
        float aqr[4];
#pragma unroll
        for (int r = 0; r < 4; r++) aqr[r] = __shfl(alpha, g * 4 + r);
#pragma unroll
        for (int nf = 0; nf < 4; nf++)
#pragma unroll
            for (int r = 0; r < 4; r++) o[nf][r] *= aqr[r];

        // lp is wave-private: drain LDS, no cross-wave barrier needed
        asm volatile("s_waitcnt lgkmcnt(0)" ::: "memory");
        __builtin_amdgcn_sched_barrier(0);

        bf16x8 pa0 = *(const bf16x8*)&lp[w][c][g * 8];
        bf16x8 pa1 = *(const bf16x8*)&lp[w][c][32 + g * 8];
#pragma unroll
        for (int nf = 0; nf < 4; nf++) {
            bf16x8 bv0 = *(const bf16x8*)&lv[nf * 16 + c][g * 8];
            bf16x8 bv1 = *(const bf16x8*)&lv[nf * 16 + c][32 + g * 8];
            o[nf] = __builtin_amdgcn_mfma_f32_16x16x32_bf16(pa0, bv0, o[nf], 0, 0, 0);
            o[nf] = __builtin_amdgcn_mfma_f32_16x16x32_bf16(pa1, bv1, o[nf], 0, 0, 0);
        }
        __syncthreads();
    }

    // out[b, n, h*64+hd] = o / l  (l lives at stat-lanes; fetch per O-row)
    float lq[4];
#pragma unroll
    for (int r = 0; r < 4; r++) lq[r] = __shfl(lr, g * 4 + r);
#pragma unroll
    for (int r = 0; r < 4; r++) {
        float inv = 1.f / lq[r];
        int n = q0 + w * 16 + g * 4 + r;
#pragma unroll
        for (int nf = 0; nf < 4; nf++)
            out[((size_t)(b * N_ + n)) * D_ + h * HD_ + nf * 16 + c] = o[nf][r] * inv;
    }
}

// ---------------- launcher ----------------------------------------------
extern "C" void kernel_launch(void* const* d_in, const int* in_sizes, int n_in,
                              void* d_out, int out_size, void* d_ws, size_t ws_size,
                              hipStream_t stream) {
    const float* x  = (const float*)d_in[0];
    const float* Wq = (const float*)d_in[1];
    const float* bq = (const float*)d_in[2];
    const float* Wk = (const float*)d_in[3];
    const float* bk = (const float*)d_in[4];
    const float* Wv = (const float*)d_in[5];
    const float* bv = (const float*)d_in[6];
    float* out = (float*)d_out;

    char* ws = (char*)d_ws;
    unsigned short* xbf  = (unsigned short*)ws;                    // 16384*768*2 = 25165824
    unsigned short* wtq  = (unsigned short*)(ws + 25165824);       // 768*768*2 each
    unsigned short* wtk  = wtq + D_ * D_;
    unsigned short* wtv  = wtk + D_ * D_;
    unsigned short* qbf  = (unsigned short*)(ws + 28704768);       // [B,H,N,64] bf16 (prescaled)
    unsigned short* kbf  = qbf + (size_t)B_ * H_ * N_ * HD_;
    unsigned short* vtbf = kbf + (size_t)B_ * H_ * N_ * HD_;       // [B,H,64,N] bf16

    cvt_x_kernel<<<6144, 256, 0, stream>>>(x, xbf);
    dim3 gw(24, 24, 3), bw(32, 8);
    wt_kernel<<<gw, bw, 0, stream>>>(Wq, Wk, Wv, wtq, wtk, wtv);
    dim3 gg(256, 12, 3);
    qkv_gemm_kernel<<<gg, 256, 0, stream>>>(xbf, wtq, wtk, wtv, bq, bk, bv, qbf, kbf, vtbf);
    dim3 ga(16, 192);
    attn_kernel<<<ga, 256, 0, stream>>>(qbf, kbf, vtbf, out);
}

// Round 6
// 220.143 us; speedup vs baseline: 1.3786x; 1.1492x over previous
//
#include <hip/hip_runtime.h>

#define B_ 16
#define N_ 1024
#define D_ 768
#define H_ 12
#define HD_ 64
// Q is pre-scaled by 0.125 * log2(e) so softmax is exp2-based.
#define QSCALE 0.18033688011112042f

typedef __attribute__((ext_vector_type(8))) __bf16 bf16x8;
typedef __attribute__((ext_vector_type(4))) float f32x4;
typedef unsigned short u16;
typedef unsigned int u32;

__device__ inline u16 f2bf(float f) {
    u32 u = __builtin_bit_cast(u32, f);
    u += 0x7fffu + ((u >> 16) & 1u);   // round-to-nearest-even
    return (u16)(u >> 16);
}

__device__ inline float fexp2(float x) {
#if __has_builtin(__builtin_amdgcn_exp2f)
    return __builtin_amdgcn_exp2f(x);
#else
    return exp2f(x);
#endif
}

__device__ inline u32 cvt_pk_bf16(float a, float b) {
    u32 r;
    asm("v_cvt_pk_bf16_f32 %0, %1, %2" : "=v"(r) : "v"(a), "v"(b));
    return r;
}

// async global->LDS, 16B per lane; LDS dest = wave-uniform base + lane*16
__device__ inline void gl_lds16(const u16* gp, u16* lp_) {
    __builtin_amdgcn_global_load_lds(
        (const __attribute__((address_space(1))) u32*)(gp),
        (__attribute__((address_space(3))) u32*)(lp_), 16, 0, 0);
}

// ---------------- kernel 1: x fp32 -> bf16 -------------------------------
__global__ __launch_bounds__(256) void cvt_x_kernel(const float* __restrict__ x,
                                                    u16* __restrict__ xbf) {
    int i = blockIdx.x * 256 + threadIdx.x;      // 8 elems per thread, exact cover
    const float4* p = (const float4*)x;
    float4 a = p[2 * i], b = p[2 * i + 1];
    union { u16 us[8]; int4 v; } u;
    u.us[0] = f2bf(a.x); u.us[1] = f2bf(a.y); u.us[2] = f2bf(a.z); u.us[3] = f2bf(a.w);
    u.us[4] = f2bf(b.x); u.us[5] = f2bf(b.y); u.us[6] = f2bf(b.z); u.us[7] = f2bf(b.w);
    ((int4*)xbf)[i] = u.v;
}

// ---------------- kernel 2: W [K][N] fp32 -> wtall [3*768][K] bf16 -------
__global__ void wt_kernel(const float* __restrict__ Wq, const float* __restrict__ Wk,
                          const float* __restrict__ Wv, u16* __restrict__ wtall) {
    const float* W = blockIdx.z == 0 ? Wq : (blockIdx.z == 1 ? Wk : Wv);
    u16* Wt = wtall + (size_t)blockIdx.z * D_ * D_;
    __shared__ u16 t[32][33];
    int n0 = blockIdx.x * 32, k0 = blockIdx.y * 32;
#pragma unroll
    for (int i = 0; i < 4; i++) {
        int k = k0 + threadIdx.y + i * 8;
        t[threadIdx.y + i * 8][threadIdx.x] = f2bf(W[k * D_ + n0 + threadIdx.x]);
    }
    __syncthreads();
#pragma unroll
    for (int i = 0; i < 4; i++) {
        int n = n0 + threadIdx.y + i * 8;
        Wt[n * D_ + k0 + threadIdx.x] = t[threadIdx.x][threadIdx.y + i * 8];
    }
}

// ---------------- kernel 3: fused QKV GEMM (m97 structure) ---------------
// C[16384, 2304] = xbf @ wtall^T, 128x128 tile, 4 waves (2x2 quadrants of 64x64),
// BK=64, global_load_lds(16B) into linear LDS.
// N-tiles 0-5 -> q (scaled, [bh][n][hd]), 6-11 -> k ([bh][n][hd]),
// 12-17 -> v written TRANSPOSED ([bh][hd][n]) via packed 8B stores.
__global__ __launch_bounds__(256) void qkv2_kernel(
    const u16* __restrict__ xbf, const u16* __restrict__ wtall,
    const float* __restrict__ bq, const float* __restrict__ bk, const float* __restrict__ bv,
    u16* __restrict__ qbf, u16* __restrict__ kbf, u16* __restrict__ vtbf) {
    __shared__ u16 lsA[128 * 64];   // [m][k] linear, 16 KB
    __shared__ u16 lsB[128 * 64];   // [n][k] linear, 16 KB

    const int nt = blockIdx.x, mt = blockIdx.y;
    const int tid = threadIdx.x, w = tid >> 6, lane = tid & 63;
    const int g = lane >> 4, c = lane & 15;
    const int wr = w >> 1, wc = w & 1;
    const int m0 = mt * 128, n0 = nt * 128;

    // per-lane global source pointers: chunk ch = (i*4+w)*64+lane, row=ch>>3, col16B=ch&7
    const u16* pa[4];
    const u16* pb[4];
#pragma unroll
    for (int i = 0; i < 4; i++) {
        int ch = (i * 4 + w) * 64 + lane;
        int row = ch >> 3, c8 = ch & 7;
        pa[i] = xbf + (size_t)(m0 + row) * D_ + c8 * 8;
        pb[i] = wtall + (size_t)(n0 + row) * D_ + c8 * 8;
    }

    f32x4 acc[4][4];
#pragma unroll
    for (int i = 0; i < 4; i++)
#pragma unroll
        for (int j = 0; j < 4; j++) acc[i][j] = (f32x4){0.f, 0.f, 0.f, 0.f};

    for (int k0 = 0; k0 < D_; k0 += 64) {
#pragma unroll
        for (int i = 0; i < 4; i++) {
            gl_lds16(pa[i], &lsA[(i * 4 + w) * 512]);
            gl_lds16(pb[i], &lsB[(i * 4 + w) * 512]);
            pa[i] += 64; pb[i] += 64;
        }
        __syncthreads();   // drains vmcnt (compiler) -> LDS tiles ready
#pragma unroll
        for (int kk = 0; kk < 2; kk++) {
            bf16x8 af[4], bfr[4];
#pragma unroll
            for (int f = 0; f < 4; f++)
                af[f] = *(const bf16x8*)&lsA[(wr * 64 + f * 16 + c) * 64 + kk * 32 + g * 8];
#pragma unroll
            for (int f = 0; f < 4; f++)
                bfr[f] = *(const bf16x8*)&lsB[(wc * 64 + f * 16 + c) * 64 + kk * 32 + g * 8];
#pragma unroll
            for (int fr = 0; fr < 4; fr++)
#pragma unroll
                for (int fc = 0; fc < 4; fc++)
                    acc[fr][fc] = __builtin_amdgcn_mfma_f32_16x16x32_bf16(
                        af[fr], bfr[fc], acc[fr][fc], 0, 0, 0);
        }
        __syncthreads();
    }

    const int mode = nt / 6;               // 0=q 1=k 2=v
    const int ncol0 = (nt % 6) * 128;      // within-mode output column base
    const float* bias = mode == 0 ? bq : (mode == 1 ? bk : bv);
    float bb[4];
#pragma unroll
    for (int fc = 0; fc < 4; fc++) bb[fc] = bias[ncol0 + wc * 64 + fc * 16 + c];

    if (mode < 2) {
        u16* outp = mode == 0 ? qbf : kbf;
        const float osc = mode == 0 ? QSCALE : 1.0f;
#pragma unroll
        for (int fc = 0; fc < 4; fc++) {
            int col = ncol0 + wc * 64 + fc * 16 + c;
            int head = col >> 6, hd = col & 63;
#pragma unroll
            for (int fr = 0; fr < 4; fr++)
#pragma unroll
                for (int rr = 0; rr < 4; rr++) {
                    int m = m0 + wr * 64 + fr * 16 + g * 4 + rr;
                    int b = m >> 10, nn = m & 1023;
                    outp[(((size_t)b * H_ + head) * N_ + nn) * HD_ + hd] =
                        f2bf((acc[fr][fc][rr] + bb[fc]) * osc);
                }
        }
    } else {
        // v transposed: D-fragment's 4 rows are m-contiguous -> one packed 8B store
#pragma unroll
        for (int fc = 0; fc < 4; fc++) {
            int col = ncol0 + wc * 64 + fc * 16 + c;
            int head = col >> 6, hd = col & 63;
#pragma unroll
            for (int fr = 0; fr < 4; fr++) {
                int m = m0 + wr * 64 + fr * 16 + g * 4;
                int b = m >> 10, nn = m & 1023;
                union { u16 us[4]; int2 v; } u;
#pragma unroll
                for (int rr = 0; rr < 4; rr++) u.us[rr] = f2bf(acc[fr][fc][rr] + bb[fc]);
                *(int2*)&vtbf[(((size_t)b * H_ + head) * HD_ + hd) * N_ + nn] = u.v;
            }
        }
    }
}

// ---------------- kernel 4: flash attention ------------------------------
// Swapped QK^T + T14 async-stage (next K/V tile loads overlap compute) +
// T13 defer-max (skip o-rescale unless tile max exceeds running max by >8).
__global__ __launch_bounds__(256) void attn_kernel(
    const u16* __restrict__ qbf, const u16* __restrict__ kbf,
    const u16* __restrict__ vtbf, float* __restrict__ out) {
    __shared__ u16 lk[64][72];      // K tile  [kv][hd]
    __shared__ u16 lv[64][72];      // Vt tile [hd][kv]
    __shared__ u16 lp[4][16][72];   // P per wave [q][kv]

    const int qt = blockIdx.x;      // 16 q-tiles
    const int bh = blockIdx.y;      // 192
    const int b = bh / H_, h = bh % H_;
    const int tid = threadIdx.x;
    const int w = tid >> 6, lane = tid & 63, g = lane >> 4, c = lane & 15;
    const int q0 = qt * 64;

    const u16* qrow = qbf + ((size_t)bh * N_ + q0 + w * 16 + c) * HD_;
    bf16x8 aq0 = *(const bf16x8*)&qrow[g * 8];
    bf16x8 aq1 = *(const bf16x8*)&qrow[32 + g * 8];

    const u16* kbase = kbf + (size_t)bh * N_ * HD_;
    const u16* vbase = vtbf + (size_t)bh * HD_ * N_;
    const int r0 = tid >> 3, c80 = (tid & 7) * 8;   // chunk tid
    const int r1 = r0 + 32;                          // chunk tid+256 (same c8)

    int4 kreg0, kreg1, vreg0, vreg1;
#define LOADT(KV) do { \
        kreg0 = *(const int4*)(kbase + (size_t)((KV) + r0) * HD_ + c80); \
        kreg1 = *(const int4*)(kbase + (size_t)((KV) + r1) * HD_ + c80); \
        vreg0 = *(const int4*)(vbase + (size_t)r0 * N_ + (KV) + c80); \
        vreg1 = *(const int4*)(vbase + (size_t)r1 * N_ + (KV) + c80); \
    } while (0)
#define WRITET do { \
        *(int4*)&lk[r0][c80] = kreg0; \
        *(int4*)&lk[r1][c80] = kreg1; \
        *(int4*)&lv[r0][c80] = vreg0; \
        *(int4*)&lv[r1][c80] = vreg1; \
    } while (0)

    f32x4 o[4];
#pragma unroll
    for (int i = 0; i < 4; i++) o[i] = (f32x4){0.f, 0.f, 0.f, 0.f};
    float mr = -3e38f, lr = 0.f;    // running stats for q = w*16+c

    LOADT(0);
    WRITET;

    for (int kv0 = 0; kv0 < N_; kv0 += 64) {
        __syncthreads();            // staging writes visible
        const bool more = (kv0 + 64) < N_;
        if (more) LOADT(kv0 + 64);  // overlaps all compute below (T14)

        // S^T = K Q^T: s[nf]: kv = nf*16+g*4+r, q = w*16+c
        f32x4 s[4];
#pragma unroll
        for (int i = 0; i < 4; i++) s[i] = (f32x4){0.f, 0.f, 0.f, 0.f};
#pragma unroll
        for (int nf = 0; nf < 4; nf++) {
            bf16x8 ak0 = *(const bf16x8*)&lk[nf * 16 + c][g * 8];
            bf16x8 ak1 = *(const bf16x8*)&lk[nf * 16 + c][32 + g * 8];
            s[nf] = __builtin_amdgcn_mfma_f32_16x16x32_bf16(ak0, aq0, s[nf], 0, 0, 0);
            s[nf] = __builtin_amdgcn_mfma_f32_16x16x32_bf16(ak1, aq1, s[nf], 0, 0, 0);
        }

        // tile max for q=w*16+c: in-lane tree + xor16/32
        f32x4 m4 = s[0];
#pragma unroll
        for (int nf = 1; nf < 4; nf++) {
            m4[0] = fmaxf(m4[0], s[nf][0]); m4[1] = fmaxf(m4[1], s[nf][1]);
            m4[2] = fmaxf(m4[2], s[nf][2]); m4[3] = fmaxf(m4[3], s[nf][3]);
        }
        float mx = fmaxf(fmaxf(m4[0], m4[1]), fmaxf(m4[2], m4[3]));
        mx = fmaxf(mx, __shfl_xor(mx, 16));
        mx = fmaxf(mx, __shfl_xor(mx, 32));

        // T13 defer-max: only rescale when some row's max grew by >8 (log2 units)
        if (__any(mx > mr + 8.0f)) {
            float mn = fmaxf(mr, mx);
            float alpha = fexp2(mr - mn);
            mr = mn;
            lr *= alpha;
            float aqr[4];
#pragma unroll
            for (int r = 0; r < 4; r++) aqr[r] = __shfl(alpha, g * 4 + r);
#pragma unroll
            for (int nf = 0; nf < 4; nf++)
#pragma unroll
                for (int r = 0; r < 4; r++) o[nf][r] *= aqr[r];
        }

        // P = exp2(S - mr); row-sum
        f32x4 rsv = (f32x4){0.f, 0.f, 0.f, 0.f};
#pragma unroll
        for (int nf = 0; nf < 4; nf++) {
#pragma unroll
            for (int r = 0; r < 4; r++) s[nf][r] = fexp2(s[nf][r] - mr);
            rsv += s[nf];
        }
        float rs = (rsv[0] + rsv[1]) + (rsv[2] + rsv[3]);
        rs += __shfl_xor(rs, 16);
        rs += __shfl_xor(rs, 32);
        lr += rs;

        // P^T -> lp[w][q][kv] packed bf16
#pragma unroll
        for (int nf = 0; nf < 4; nf++) {
            union { u32 ui[2]; int2 v; } u;
            u.ui[0] = cvt_pk_bf16(s[nf][0], s[nf][1]);
            u.ui[1] = cvt_pk_bf16(s[nf][2], s[nf][3]);
            *(int2*)&lp[w][c][nf * 16 + g * 4] = u.v;
        }

        // lp is wave-private: drain LDS, fence the scheduler (guide rule 18)
        asm volatile("s_waitcnt lgkmcnt(0)" ::: "memory");
        __builtin_amdgcn_sched_barrier(0);

        bf16x8 pa0 = *(const bf16x8*)&lp[w][c][g * 8];
        bf16x8 pa1 = *(const bf16x8*)&lp[w][c][32 + g * 8];
#pragma unroll
        for (int nf = 0; nf < 4; nf++) {
            bf16x8 bv0 = *(const bf16x8*)&lv[nf * 16 + c][g * 8];
            bf16x8 bv1 = *(const bf16x8*)&lv[nf * 16 + c][32 + g * 8];
            o[nf] = __builtin_amdgcn_mfma_f32_16x16x32_bf16(pa0, bv0, o[nf], 0, 0, 0);
            o[nf] = __builtin_amdgcn_mfma_f32_16x16x32_bf16(pa1, bv1, o[nf], 0, 0, 0);
        }
        __syncthreads();            // all waves done reading lk/lv
        if (more) WRITET;           // stage next tile (visible after top sync)
    }
#undef LOADT
#undef WRITET

    // out[b, n, h*64+hd] = o / l
    float lq[4];
#pragma unroll
    for (int r = 0; r < 4; r++) lq[r] = __shfl(lr, g * 4 + r);
#pragma unroll
    for (int r = 0; r < 4; r++) {
        float inv = 1.f / lq[r];
        int n = q0 + w * 16 + g * 4 + r;
#pragma unroll
        for (int nf = 0; nf < 4; nf++)
            out[((size_t)(b * N_ + n)) * D_ + h * HD_ + nf * 16 + c] = o[nf][r] * inv;
    }
}

// ---------------- launcher ----------------------------------------------
extern "C" void kernel_launch(void* const* d_in, const int* in_sizes, int n_in,
                              void* d_out, int out_size, void* d_ws, size_t ws_size,
                              hipStream_t stream) {
    const float* x  = (const float*)d_in[0];
    const float* Wq = (const float*)d_in[1];
    const float* bq = (const float*)d_in[2];
    const float* Wk = (const float*)d_in[3];
    const float* bk = (const float*)d_in[4];
    const float* Wv = (const float*)d_in[5];
    const float* bv = (const float*)d_in[6];
    float* out = (float*)d_out;

    char* ws = (char*)d_ws;
    u16* xbf   = (u16*)ws;                      // 16384*768*2 = 25165824 B
    u16* wtall = (u16*)(ws + 25165824);         // 2304*768*2  =  3538944 B
    u16* qbf   = (u16*)(ws + 28704768);         // [B,H,N,64] bf16 (prescaled)
    u16* kbf   = (u16*)(ws + 53870592);         // [B,H,N,64] bf16
    u16* vtbf  = (u16*)(ws + 79036416);         // [B,H,64,N] bf16

    cvt_x_kernel<<<6144, 256, 0, stream>>>(x, xbf);
    dim3 gw(24, 24, 3), bw(32, 8);
    wt_kernel<<<gw, bw, 0, stream>>>(Wq, Wk, Wv, wtall);
    dim3 gg(18, 128);
    qkv2_kernel<<<gg, 256, 0, stream>>>(xbf, wtall, bq, bk, bv, qbf, kbf, vtbf);
    dim3 ga(16, 192);
    attn_kernel<<<ga, 256, 0, stream>>>(qbf, kbf, vtbf, out);
}

// Round 7
// 214.640 us; speedup vs baseline: 1.4139x; 1.0256x over previous
//
#include <hip/hip_runtime.h>

#define B_ 16
#define N_ 1024
#define D_ 768
#define H_ 12
#define HD_ 64
// Q is pre-scaled by 0.125 * log2(e) so softmax is exp2-based.
#define QSCALE 0.18033688011112042f

typedef __attribute__((ext_vector_type(8))) __bf16 bf16x8;
typedef __attribute__((ext_vector_type(4))) float f32x4;
typedef unsigned short u16;
typedef unsigned int u32;

__device__ inline u16 f2bf(float f) {
    u32 u = __builtin_bit_cast(u32, f);
    u += 0x7fffu + ((u >> 16) & 1u);   // round-to-nearest-even
    return (u16)(u >> 16);
}

__device__ inline float fexp2(float x) {
#if __has_builtin(__builtin_amdgcn_exp2f)
    return __builtin_amdgcn_exp2f(x);
#else
    return exp2f(x);
#endif
}

__device__ inline u32 cvt_pk_bf16(float a, float b) {
    u32 r;
    asm("v_cvt_pk_bf16_f32 %0, %1, %2" : "=v"(r) : "v"(a), "v"(b));
    return r;
}

// async global->LDS, 16B per lane; LDS dest = wave-uniform base + lane*16
__device__ inline void gl_lds16(const u16* gp, u16* lp_) {
    __builtin_amdgcn_global_load_lds(
        (const __attribute__((address_space(1))) u32*)(gp),
        (__attribute__((address_space(3))) u32*)(lp_), 16, 0, 0);
}

// ---------------- kernel 1: x fp32 -> bf16 -------------------------------
__global__ __launch_bounds__(256) void cvt_x_kernel(const float* __restrict__ x,
                                                    u16* __restrict__ xbf) {
    int i = blockIdx.x * 256 + threadIdx.x;      // 8 elems per thread, exact cover
    const float4* p = (const float4*)x;
    float4 a = p[2 * i], b = p[2 * i + 1];
    union { u16 us[8]; int4 v; } u;
    u.us[0] = f2bf(a.x); u.us[1] = f2bf(a.y); u.us[2] = f2bf(a.z); u.us[3] = f2bf(a.w);
    u.us[4] = f2bf(b.x); u.us[5] = f2bf(b.y); u.us[6] = f2bf(b.z); u.us[7] = f2bf(b.w);
    ((int4*)xbf)[i] = u.v;
}

// ---------------- kernel 2: W [K][N] fp32 -> wtall [3*768][K] bf16 -------
__global__ void wt_kernel(const float* __restrict__ Wq, const float* __restrict__ Wk,
                          const float* __restrict__ Wv, u16* __restrict__ wtall) {
    const float* W = blockIdx.z == 0 ? Wq : (blockIdx.z == 1 ? Wk : Wv);
    u16* Wt = wtall + (size_t)blockIdx.z * D_ * D_;
    __shared__ u16 t[32][33];
    int n0 = blockIdx.x * 32, k0 = blockIdx.y * 32;
#pragma unroll
    for (int i = 0; i < 4; i++) {
        int k = k0 + threadIdx.y + i * 8;
        t[threadIdx.y + i * 8][threadIdx.x] = f2bf(W[k * D_ + n0 + threadIdx.x]);
    }
    __syncthreads();
#pragma unroll
    for (int i = 0; i < 4; i++) {
        int n = n0 + threadIdx.y + i * 8;
        Wt[n * D_ + k0 + threadIdx.x] = t[threadIdx.x][threadIdx.y + i * 8];
    }
}

// ---------------- kernel 3: fused QKV GEMM (m97 structure) ---------------
__global__ __launch_bounds__(256) void qkv2_kernel(
    const u16* __restrict__ xbf, const u16* __restrict__ wtall,
    const float* __restrict__ bq, const float* __restrict__ bk, const float* __restrict__ bv,
    u16* __restrict__ qbf, u16* __restrict__ kbf, u16* __restrict__ vtbf) {
    __shared__ u16 lsA[128 * 64];   // [m][k] linear, 16 KB
    __shared__ u16 lsB[128 * 64];   // [n][k] linear, 16 KB

    const int nt = blockIdx.x, mt = blockIdx.y;
    const int tid = threadIdx.x, w = tid >> 6, lane = tid & 63;
    const int g = lane >> 4, c = lane & 15;
    const int wr = w >> 1, wc = w & 1;
    const int m0 = mt * 128, n0 = nt * 128;

    const u16* pa[4];
    const u16* pb[4];
#pragma unroll
    for (int i = 0; i < 4; i++) {
        int ch = (i * 4 + w) * 64 + lane;
        int row = ch >> 3, c8 = ch & 7;
        pa[i] = xbf + (size_t)(m0 + row) * D_ + c8 * 8;
        pb[i] = wtall + (size_t)(n0 + row) * D_ + c8 * 8;
    }

    f32x4 acc[4][4];
#pragma unroll
    for (int i = 0; i < 4; i++)
#pragma unroll
        for (int j = 0; j < 4; j++) acc[i][j] = (f32x4){0.f, 0.f, 0.f, 0.f};

    for (int k0 = 0; k0 < D_; k0 += 64) {
#pragma unroll
        for (int i = 0; i < 4; i++) {
            gl_lds16(pa[i], &lsA[(i * 4 + w) * 512]);
            gl_lds16(pb[i], &lsB[(i * 4 + w) * 512]);
            pa[i] += 64; pb[i] += 64;
        }
        __syncthreads();
#pragma unroll
        for (int kk = 0; kk < 2; kk++) {
            bf16x8 af[4], bfr[4];
#pragma unroll
            for (int f = 0; f < 4; f++)
                af[f] = *(const bf16x8*)&lsA[(wr * 64 + f * 16 + c) * 64 + kk * 32 + g * 8];
#pragma unroll
            for (int f = 0; f < 4; f++)
                bfr[f] = *(const bf16x8*)&lsB[(wc * 64 + f * 16 + c) * 64 + kk * 32 + g * 8];
#pragma unroll
            for (int fr = 0; fr < 4; fr++)
#pragma unroll
                for (int fc = 0; fc < 4; fc++)
                    acc[fr][fc] = __builtin_amdgcn_mfma_f32_16x16x32_bf16(
                        af[fr], bfr[fc], acc[fr][fc], 0, 0, 0);
        }
        __syncthreads();
    }

    const int mode = nt / 6;               // 0=q 1=k 2=v
    const int ncol0 = (nt % 6) * 128;
    const float* bias = mode == 0 ? bq : (mode == 1 ? bk : bv);
    float bb[4];
#pragma unroll
    for (int fc = 0; fc < 4; fc++) bb[fc] = bias[ncol0 + wc * 64 + fc * 16 + c];

    if (mode < 2) {
        u16* outp = mode == 0 ? qbf : kbf;
        const float osc = mode == 0 ? QSCALE : 1.0f;
#pragma unroll
        for (int fc = 0; fc < 4; fc++) {
            int col = ncol0 + wc * 64 + fc * 16 + c;
            int head = col >> 6, hd = col & 63;
#pragma unroll
            for (int fr = 0; fr < 4; fr++)
#pragma unroll
                for (int rr = 0; rr < 4; rr++) {
                    int m = m0 + wr * 64 + fr * 16 + g * 4 + rr;
                    int b = m >> 10, nn = m & 1023;
                    outp[(((size_t)b * H_ + head) * N_ + nn) * HD_ + hd] =
                        f2bf((acc[fr][fc][rr] + bb[fc]) * osc);
                }
        }
    } else {
#pragma unroll
        for (int fc = 0; fc < 4; fc++) {
            int col = ncol0 + wc * 64 + fc * 16 + c;
            int head = col >> 6, hd = col & 63;
#pragma unroll
            for (int fr = 0; fr < 4; fr++) {
                int m = m0 + wr * 64 + fr * 16 + g * 4;
                int b = m >> 10, nn = m & 1023;
                union { u16 us[4]; int2 v; } u;
#pragma unroll
                for (int rr = 0; rr < 4; rr++) u.us[rr] = f2bf(acc[fr][fc][rr] + bb[fc]);
                *(int2*)&vtbf[(((size_t)b * H_ + head) * HD_ + hd) * N_ + nn] = u.v;
            }
        }
    }
}

// ---------------- kernel 4: flash attention ------------------------------
// 4 waves x 32 q-rows (2 subtiles of 16), 128 q-rows/block, KVBLK=64.
// Swapped QK^T (S^T = K Q^T, row stats in-lane) + T13 defer-max + T14
// async-stage. PV uses a permuted k-slot mapping so the A-fragment is
// built ENTIRELY from the lane's own P registers (no LDS/shuffle for P):
//   k = g*8+j  <->  kv = 4g+j (j<4) | 16+4g+(j-4) (j>=4)   [+32 for half 1]
// B-side compensates: lv columns read at {4g, 16+4g} / {32+4g, 48+4g}.
__global__ __launch_bounds__(256) void attn_kernel(
    const u16* __restrict__ qbf, const u16* __restrict__ kbf,
    const u16* __restrict__ vtbf, float* __restrict__ out) {
    __shared__ u16 lk[64][72];      // K tile  [kv][hd]
    __shared__ u16 lv[64][72];      // Vt tile [hd][kv]

    const int qt = blockIdx.x;      // 8 q-tiles of 128
    const int bh = blockIdx.y;      // 192
    const int b = bh / H_, h = bh % H_;
    const int tid = threadIdx.x;
    const int w = tid >> 6, lane = tid & 63, g = lane >> 4, c = lane & 15;
    const int q0 = qt * 128;

    // Q fragments (B-operand), 2 subtiles: q = q0 + w*32 + ss*16 + c
    bf16x8 aq[2][2];
#pragma unroll
    for (int ss = 0; ss < 2; ss++) {
        const u16* qr = qbf + ((size_t)bh * N_ + q0 + w * 32 + ss * 16 + c) * HD_;
        aq[ss][0] = *(const bf16x8*)&qr[g * 8];
        aq[ss][1] = *(const bf16x8*)&qr[32 + g * 8];
    }

    const u16* kbase = kbf + (size_t)bh * N_ * HD_;
    const u16* vbase = vtbf + (size_t)bh * HD_ * N_;
    const int r0 = tid >> 3, c80 = (tid & 7) * 8;
    const int r1 = r0 + 32;

    int4 kreg0, kreg1, vreg0, vreg1;
#define LOADT(KV) do { \
        kreg0 = *(const int4*)(kbase + (size_t)((KV) + r0) * HD_ + c80); \
        kreg1 = *(const int4*)(kbase + (size_t)((KV) + r1) * HD_ + c80); \
        vreg0 = *(const int4*)(vbase + (size_t)r0 * N_ + (KV) + c80); \
        vreg1 = *(const int4*)(vbase + (size_t)r1 * N_ + (KV) + c80); \
    } while (0)
#define WRITET do { \
        *(int4*)&lk[r0][c80] = kreg0; \
        *(int4*)&lk[r1][c80] = kreg1; \
        *(int4*)&lv[r0][c80] = vreg0; \
        *(int4*)&lv[r1][c80] = vreg1; \
    } while (0)

    f32x4 o[2][4];
#pragma unroll
    for (int ss = 0; ss < 2; ss++)
#pragma unroll
        for (int i = 0; i < 4; i++) o[ss][i] = (f32x4){0.f, 0.f, 0.f, 0.f};
    float mr[2] = {-3e38f, -3e38f}, lr[2] = {0.f, 0.f};

    LOADT(0);
    WRITET;

    for (int kv0 = 0; kv0 < N_; kv0 += 64) {
        __syncthreads();
        const bool more = (kv0 + 64) < N_;
        if (more) LOADT(kv0 + 64);   // T14: overlaps all compute below

        // S^T = K Q^T; sc[ss][nf]: kv = nf*16+g*4+r, q = w*32+ss*16+c
        f32x4 sc[2][4];
#pragma unroll
        for (int ss = 0; ss < 2; ss++)
#pragma unroll
            for (int i = 0; i < 4; i++) sc[ss][i] = (f32x4){0.f, 0.f, 0.f, 0.f};
#pragma unroll
        for (int nf = 0; nf < 4; nf++) {
            bf16x8 ak0 = *(const bf16x8*)&lk[nf * 16 + c][g * 8];
            bf16x8 ak1 = *(const bf16x8*)&lk[nf * 16 + c][32 + g * 8];
#pragma unroll
            for (int ss = 0; ss < 2; ss++) {
                sc[ss][nf] = __builtin_amdgcn_mfma_f32_16x16x32_bf16(ak0, aq[ss][0], sc[ss][nf], 0, 0, 0);
                sc[ss][nf] = __builtin_amdgcn_mfma_f32_16x16x32_bf16(ak1, aq[ss][1], sc[ss][nf], 0, 0, 0);
            }
        }

        // tile max per sub (in-lane tree + xor16/32)
        float mx[2];
#pragma unroll
        for (int ss = 0; ss < 2; ss++) {
            f32x4 m4 = sc[ss][0];
#pragma unroll
            for (int nf = 1; nf < 4; nf++) {
                m4[0] = fmaxf(m4[0], sc[ss][nf][0]); m4[1] = fmaxf(m4[1], sc[ss][nf][1]);
                m4[2] = fmaxf(m4[2], sc[ss][nf][2]); m4[3] = fmaxf(m4[3], sc[ss][nf][3]);
            }
            float v = fmaxf(fmaxf(m4[0], m4[1]), fmaxf(m4[2], m4[3]));
            v = fmaxf(v, __shfl_xor(v, 16));
            v = fmaxf(v, __shfl_xor(v, 32));
            mx[ss] = v;
        }

        // T13 defer-max
        if (__any(mx[0] > mr[0] + 8.0f || mx[1] > mr[1] + 8.0f)) {
#pragma unroll
            for (int ss = 0; ss < 2; ss++) {
                float mn = fmaxf(mr[ss], mx[ss]);
                float alpha = fexp2(mr[ss] - mn);
                mr[ss] = mn;
                lr[ss] *= alpha;
                float aqr[4];
#pragma unroll
                for (int r = 0; r < 4; r++) aqr[r] = __shfl(alpha, g * 4 + r);
#pragma unroll
                for (int nf = 0; nf < 4; nf++)
#pragma unroll
                    for (int r = 0; r < 4; r++) o[ss][nf][r] *= aqr[r];
            }
        }

        // P = exp2(S - mr); row sums; pack to bf16 pairs (own-lane only)
        u32 pkk[2][4][2];
#pragma unroll
        for (int ss = 0; ss < 2; ss++) {
            f32x4 rsv = (f32x4){0.f, 0.f, 0.f, 0.f};
#pragma unroll
            for (int nf = 0; nf < 4; nf++) {
#pragma unroll
                for (int r = 0; r < 4; r++) sc[ss][nf][r] = fexp2(sc[ss][nf][r] - mr[ss]);
                rsv += sc[ss][nf];
                pkk[ss][nf][0] = cvt_pk_bf16(sc[ss][nf][0], sc[ss][nf][1]);
                pkk[ss][nf][1] = cvt_pk_bf16(sc[ss][nf][2], sc[ss][nf][3]);
            }
            float rs = (rsv[0] + rsv[1]) + (rsv[2] + rsv[3]);
            rs += __shfl_xor(rs, 16);
            rs += __shfl_xor(rs, 32);
            lr[ss] += rs;
        }

        // A-fragments from own registers (permuted k-slots)
        bf16x8 pa[2][2];
#pragma unroll
        for (int ss = 0; ss < 2; ss++) {
            union { u32 ui[4]; bf16x8 v; } u0, u1;
            u0.ui[0] = pkk[ss][0][0]; u0.ui[1] = pkk[ss][0][1];
            u0.ui[2] = pkk[ss][1][0]; u0.ui[3] = pkk[ss][1][1];
            u1.ui[0] = pkk[ss][2][0]; u1.ui[1] = pkk[ss][2][1];
            u1.ui[2] = pkk[ss][3][0]; u1.ui[3] = pkk[ss][3][1];
            pa[ss][0] = u0.v; pa[ss][1] = u1.v;
        }

        // PV: B-side reads lv columns in the SAME permuted kv order
#pragma unroll
        for (int nf = 0; nf < 4; nf++) {
            union { int2 d[2]; bf16x8 v; } b0, b1;
            b0.d[0] = *(const int2*)&lv[nf * 16 + c][4 * g];
            b0.d[1] = *(const int2*)&lv[nf * 16 + c][16 + 4 * g];
            b1.d[0] = *(const int2*)&lv[nf * 16 + c][32 + 4 * g];
            b1.d[1] = *(const int2*)&lv[nf * 16 + c][48 + 4 * g];
#pragma unroll
            for (int ss = 0; ss < 2; ss++) {
                o[ss][nf] = __builtin_amdgcn_mfma_f32_16x16x32_bf16(pa[ss][0], b0.v, o[ss][nf], 0, 0, 0);
                o[ss][nf] = __builtin_amdgcn_mfma_f32_16x16x32_bf16(pa[ss][1], b1.v, o[ss][nf], 0, 0, 0);
            }
        }
        __syncthreads();
        if (more) WRITET;
    }
#undef LOADT
#undef WRITET

    // out[b, n, h*64+hd] = o / l
#pragma unroll
    for (int ss = 0; ss < 2; ss++) {
        float lq[4];
#pragma unroll
        for (int r = 0; r < 4; r++) lq[r] = __shfl(lr[ss], g * 4 + r);
#pragma unroll
        for (int r = 0; r < 4; r++) {
            float inv = 1.f / lq[r];
            int n = q0 + w * 32 + ss * 16 + g * 4 + r;
#pragma unroll
            for (int nf = 0; nf < 4; nf++)
                out[((size_t)(b * N_ + n)) * D_ + h * HD_ + nf * 16 + c] = o[ss][nf][r] * inv;
        }
    }
}

// ---------------- launcher ----------------------------------------------
extern "C" void kernel_launch(void* const* d_in, const int* in_sizes, int n_in,
                              void* d_out, int out_size, void* d_ws, size_t ws_size,
                              hipStream_t stream) {
    const float* x  = (const float*)d_in[0];
    const float* Wq = (const float*)d_in[1];
    const float* bq = (const float*)d_in[2];
    const float* Wk = (const float*)d_in[3];
    const float* bk = (const float*)d_in[4];
    const float* Wv = (const float*)d_in[5];
    const float* bv = (const float*)d_in[6];
    float* out = (float*)d_out;

    char* ws = (char*)d_ws;
    u16* xbf   = (u16*)ws;                      // 16384*768*2 = 25165824 B
    u16* wtall = (u16*)(ws + 25165824);         // 2304*768*2  =  3538944 B
    u16* qbf   = (u16*)(ws + 28704768);         // [B,H,N,64] bf16 (prescaled)
    u16* kbf   = (u16*)(ws + 53870592);         // [B,H,N,64] bf16
    u16* vtbf  = (u16*)(ws + 79036416);         // [B,H,64,N] bf16

    cvt_x_kernel<<<6144, 256, 0, stream>>>(x, xbf);
    dim3 gw(24, 24, 3), bw(32, 8);
    wt_kernel<<<gw, bw, 0, stream>>>(Wq, Wk, Wv, wtall);
    dim3 gg(18, 128);
    qkv2_kernel<<<gg, 256, 0, stream>>>(xbf, wtall, bq, bk, bv, qbf, kbf, vtbf);
    dim3 ga(8, 192);
    attn_kernel<<<ga, 256, 0, stream>>>(qbf, kbf, vtbf, out);
}

// Round 8
// 205.524 us; speedup vs baseline: 1.4766x; 1.0444x over previous
//
#include <hip/hip_runtime.h>

#define B_ 16
#define N_ 1024
#define D_ 768
#define H_ 12
#define HD_ 64
// Q is pre-scaled by 0.125 * log2(e) so softmax is exp2-based.
#define QSCALE 0.18033688011112042f

typedef __attribute__((ext_vector_type(8))) __bf16 bf16x8;
typedef __attribute__((ext_vector_type(4))) float f32x4;
typedef unsigned short u16;
typedef unsigned int u32;

__device__ inline u16 f2bf(float f) {
    u32 u = __builtin_bit_cast(u32, f);
    u += 0x7fffu + ((u >> 16) & 1u);   // round-to-nearest-even
    return (u16)(u >> 16);
}

__device__ inline float fexp2(float x) {
#if __has_builtin(__builtin_amdgcn_exp2f)
    return __builtin_amdgcn_exp2f(x);
#else
    return exp2f(x);
#endif
}

__device__ inline u32 cvt_pk_bf16(float a, float b) {
    u32 r;
    asm("v_cvt_pk_bf16_f32 %0, %1, %2" : "=v"(r) : "v"(a), "v"(b));
    return r;
}

// async global->LDS, 16B per lane; LDS dest = wave-uniform base + lane*16
__device__ inline void gl_lds16(const u16* gp, u16* lp_) {
    __builtin_amdgcn_global_load_lds(
        (const __attribute__((address_space(1))) u32*)(gp),
        (__attribute__((address_space(3))) u32*)(lp_), 16, 0, 0);
}

// ---------------- kernel 1: x fp32 -> bf16 -------------------------------
__global__ __launch_bounds__(256) void cvt_x_kernel(const float* __restrict__ x,
                                                    u16* __restrict__ xbf) {
    int i = blockIdx.x * 256 + threadIdx.x;      // 8 elems per thread, exact cover
    const float4* p = (const float4*)x;
    float4 a = p[2 * i], b = p[2 * i + 1];
    union { u16 us[8]; int4 v; } u;
    u.us[0] = f2bf(a.x); u.us[1] = f2bf(a.y); u.us[2] = f2bf(a.z); u.us[3] = f2bf(a.w);
    u.us[4] = f2bf(b.x); u.us[5] = f2bf(b.y); u.us[6] = f2bf(b.z); u.us[7] = f2bf(b.w);
    ((int4*)xbf)[i] = u.v;
}

// ---------------- kernel 2: W [K][N] fp32 -> wtall [3*768][K] bf16 -------
__global__ void wt_kernel(const float* __restrict__ Wq, const float* __restrict__ Wk,
                          const float* __restrict__ Wv, u16* __restrict__ wtall) {
    const float* W = blockIdx.z == 0 ? Wq : (blockIdx.z == 1 ? Wk : Wv);
    u16* Wt = wtall + (size_t)blockIdx.z * D_ * D_;
    __shared__ u16 t[32][33];
    int n0 = blockIdx.x * 32, k0 = blockIdx.y * 32;
#pragma unroll
    for (int i = 0; i < 4; i++) {
        int k = k0 + threadIdx.y + i * 8;
        t[threadIdx.y + i * 8][threadIdx.x] = f2bf(W[k * D_ + n0 + threadIdx.x]);
    }
    __syncthreads();
#pragma unroll
    for (int i = 0; i < 4; i++) {
        int n = n0 + threadIdx.y + i * 8;
        Wt[n * D_ + k0 + threadIdx.x] = t[threadIdx.x][threadIdx.y + i * 8];
    }
}

// ---------------- kernel 3: fused QKV GEMM (m97 structure) ---------------
__global__ __launch_bounds__(256) void qkv2_kernel(
    const u16* __restrict__ xbf, const u16* __restrict__ wtall,
    const float* __restrict__ bq, const float* __restrict__ bk, const float* __restrict__ bv,
    u16* __restrict__ qbf, u16* __restrict__ kbf, u16* __restrict__ vtbf) {
    __shared__ u16 lsA[128 * 64];   // [m][k] linear, 16 KB
    __shared__ u16 lsB[128 * 64];   // [n][k] linear, 16 KB

    const int nt = blockIdx.x, mt = blockIdx.y;
    const int tid = threadIdx.x, w = tid >> 6, lane = tid & 63;
    const int g = lane >> 4, c = lane & 15;
    const int wr = w >> 1, wc = w & 1;
    const int m0 = mt * 128, n0 = nt * 128;

    const u16* pa[4];
    const u16* pb[4];
#pragma unroll
    for (int i = 0; i < 4; i++) {
        int ch = (i * 4 + w) * 64 + lane;
        int row = ch >> 3, c8 = ch & 7;
        pa[i] = xbf + (size_t)(m0 + row) * D_ + c8 * 8;
        pb[i] = wtall + (size_t)(n0 + row) * D_ + c8 * 8;
    }

    f32x4 acc[4][4];
#pragma unroll
    for (int i = 0; i < 4; i++)
#pragma unroll
        for (int j = 0; j < 4; j++) acc[i][j] = (f32x4){0.f, 0.f, 0.f, 0.f};

    for (int k0 = 0; k0 < D_; k0 += 64) {
#pragma unroll
        for (int i = 0; i < 4; i++) {
            gl_lds16(pa[i], &lsA[(i * 4 + w) * 512]);
            gl_lds16(pb[i], &lsB[(i * 4 + w) * 512]);
            pa[i] += 64; pb[i] += 64;
        }
        __syncthreads();
#pragma unroll
        for (int kk = 0; kk < 2; kk++) {
            bf16x8 af[4], bfr[4];
#pragma unroll
            for (int f = 0; f < 4; f++)
                af[f] = *(const bf16x8*)&lsA[(wr * 64 + f * 16 + c) * 64 + kk * 32 + g * 8];
#pragma unroll
            for (int f = 0; f < 4; f++)
                bfr[f] = *(const bf16x8*)&lsB[(wc * 64 + f * 16 + c) * 64 + kk * 32 + g * 8];
#pragma unroll
            for (int fr = 0; fr < 4; fr++)
#pragma unroll
                for (int fc = 0; fc < 4; fc++)
                    acc[fr][fc] = __builtin_amdgcn_mfma_f32_16x16x32_bf16(
                        af[fr], bfr[fc], acc[fr][fc], 0, 0, 0);
        }
        __syncthreads();
    }

    const int mode = nt / 6;               // 0=q 1=k 2=v
    const int ncol0 = (nt % 6) * 128;
    const float* bias = mode == 0 ? bq : (mode == 1 ? bk : bv);
    float bb[4];
#pragma unroll
    for (int fc = 0; fc < 4; fc++) bb[fc] = bias[ncol0 + wc * 64 + fc * 16 + c];

    if (mode < 2) {
        u16* outp = mode == 0 ? qbf : kbf;
        const float osc = mode == 0 ? QSCALE : 1.0f;
#pragma unroll
        for (int fc = 0; fc < 4; fc++) {
            int col = ncol0 + wc * 64 + fc * 16 + c;
            int head = col >> 6, hd = col & 63;
#pragma unroll
            for (int fr = 0; fr < 4; fr++)
#pragma unroll
                for (int rr = 0; rr < 4; rr++) {
                    int m = m0 + wr * 64 + fr * 16 + g * 4 + rr;
                    int b = m >> 10, nn = m & 1023;
                    outp[(((size_t)b * H_ + head) * N_ + nn) * HD_ + hd] =
                        f2bf((acc[fr][fc][rr] + bb[fc]) * osc);
                }
        }
    } else {
#pragma unroll
        for (int fc = 0; fc < 4; fc++) {
            int col = ncol0 + wc * 64 + fc * 16 + c;
            int head = col >> 6, hd = col & 63;
#pragma unroll
            for (int fr = 0; fr < 4; fr++) {
                int m = m0 + wr * 64 + fr * 16 + g * 4;
                int b = m >> 10, nn = m & 1023;
                union { u16 us[4]; int2 v; } u;
#pragma unroll
                for (int rr = 0; rr < 4; rr++) u.us[rr] = f2bf(acc[fr][fc][rr] + bb[fc]);
                *(int2*)&vtbf[(((size_t)b * H_ + head) * HD_ + hd) * N_ + nn] = u.v;
            }
        }
    }
}

// ---------------- kernel 4: flash attention ------------------------------
// 4 waves x 32 q-rows, 128 q-rows/block. Swapped QK^T, own-register PV
// A-fragments (permuted k-slots), T13 defer-max, T14 async-stage.
// NEW: LDS double-buffer -> ONE barrier per KV tile; grid is (bh, qt) so
// all q-tiles of one bh map to the same XCD (linear id % 8 == bh % 8).
__global__ __launch_bounds__(256) void attn_kernel(
    const u16* __restrict__ qbf, const u16* __restrict__ kbf,
    const u16* __restrict__ vtbf, float* __restrict__ out) {
    __shared__ u16 lk[2][64][72];   // K tiles  [buf][kv][hd]
    __shared__ u16 lv[2][64][72];   // Vt tiles [buf][hd][kv]

    const int bh = blockIdx.x;      // 192 (x-major: same-bh blocks share XCD)
    const int qt = blockIdx.y;      // 8 q-tiles of 128
    const int b = bh / H_, h = bh % H_;
    const int tid = threadIdx.x;
    const int w = tid >> 6, lane = tid & 63, g = lane >> 4, c = lane & 15;
    const int q0 = qt * 128;

    // Q fragments (B-operand), 2 subtiles: q = q0 + w*32 + ss*16 + c
    bf16x8 aq[2][2];
#pragma unroll
    for (int ss = 0; ss < 2; ss++) {
        const u16* qr = qbf + ((size_t)bh * N_ + q0 + w * 32 + ss * 16 + c) * HD_;
        aq[ss][0] = *(const bf16x8*)&qr[g * 8];
        aq[ss][1] = *(const bf16x8*)&qr[32 + g * 8];
    }

    const u16* kbase = kbf + (size_t)bh * N_ * HD_;
    const u16* vbase = vtbf + (size_t)bh * HD_ * N_;
    const int r0 = tid >> 3, c80 = (tid & 7) * 8;
    const int r1 = r0 + 32;

    int4 kreg0, kreg1, vreg0, vreg1;
#define LOADT(KV) do { \
        kreg0 = *(const int4*)(kbase + (size_t)((KV) + r0) * HD_ + c80); \
        kreg1 = *(const int4*)(kbase + (size_t)((KV) + r1) * HD_ + c80); \
        vreg0 = *(const int4*)(vbase + (size_t)r0 * N_ + (KV) + c80); \
        vreg1 = *(const int4*)(vbase + (size_t)r1 * N_ + (KV) + c80); \
    } while (0)
#define WRITET(bi) do { \
        *(int4*)&lk[bi][r0][c80] = kreg0; \
        *(int4*)&lk[bi][r1][c80] = kreg1; \
        *(int4*)&lv[bi][r0][c80] = vreg0; \
        *(int4*)&lv[bi][r1][c80] = vreg1; \
    } while (0)

    f32x4 o[2][4];
#pragma unroll
    for (int ss = 0; ss < 2; ss++)
#pragma unroll
        for (int i = 0; i < 4; i++) o[ss][i] = (f32x4){0.f, 0.f, 0.f, 0.f};
    float mr[2] = {-3e38f, -3e38f}, lr[2] = {0.f, 0.f};

    LOADT(0);
    WRITET(0);
    __syncthreads();
    int cur = 0;

    for (int kv0 = 0; kv0 < N_; kv0 += 64) {
        const bool more = (kv0 + 64) < N_;
        if (more) LOADT(kv0 + 64);   // T14: latency hidden under this tile

        // S^T = K Q^T; sc[ss][nf]: kv = nf*16+g*4+r, q = w*32+ss*16+c
        f32x4 sc[2][4];
#pragma unroll
        for (int ss = 0; ss < 2; ss++)
#pragma unroll
            for (int i = 0; i < 4; i++) sc[ss][i] = (f32x4){0.f, 0.f, 0.f, 0.f};
#pragma unroll
        for (int nf = 0; nf < 4; nf++) {
            bf16x8 ak0 = *(const bf16x8*)&lk[cur][nf * 16 + c][g * 8];
            bf16x8 ak1 = *(const bf16x8*)&lk[cur][nf * 16 + c][32 + g * 8];
#pragma unroll
            for (int ss = 0; ss < 2; ss++) {
                sc[ss][nf] = __builtin_amdgcn_mfma_f32_16x16x32_bf16(ak0, aq[ss][0], sc[ss][nf], 0, 0, 0);
                sc[ss][nf] = __builtin_amdgcn_mfma_f32_16x16x32_bf16(ak1, aq[ss][1], sc[ss][nf], 0, 0, 0);
            }
        }

        // tile max per sub (in-lane tree + xor16/32)
        float mx[2];
#pragma unroll
        for (int ss = 0; ss < 2; ss++) {
            f32x4 m4 = sc[ss][0];
#pragma unroll
            for (int nf = 1; nf < 4; nf++) {
                m4[0] = fmaxf(m4[0], sc[ss][nf][0]); m4[1] = fmaxf(m4[1], sc[ss][nf][1]);
                m4[2] = fmaxf(m4[2], sc[ss][nf][2]); m4[3] = fmaxf(m4[3], sc[ss][nf][3]);
            }
            float v = fmaxf(fmaxf(m4[0], m4[1]), fmaxf(m4[2], m4[3]));
            v = fmaxf(v, __shfl_xor(v, 16));
            v = fmaxf(v, __shfl_xor(v, 32));
            mx[ss] = v;
        }

        // T13 defer-max
        if (__any(mx[0] > mr[0] + 8.0f || mx[1] > mr[1] + 8.0f)) {
#pragma unroll
            for (int ss = 0; ss < 2; ss++) {
                float mn = fmaxf(mr[ss], mx[ss]);
                float alpha = fexp2(mr[ss] - mn);
                mr[ss] = mn;
                lr[ss] *= alpha;
                float aqr[4];
#pragma unroll
                for (int r = 0; r < 4; r++) aqr[r] = __shfl(alpha, g * 4 + r);
#pragma unroll
                for (int nf = 0; nf < 4; nf++)
#pragma unroll
                    for (int r = 0; r < 4; r++) o[ss][nf][r] *= aqr[r];
            }
        }

        // P = exp2(S - mr); row sums; pack to bf16 pairs (own-lane only)
        u32 pkk[2][4][2];
#pragma unroll
        for (int ss = 0; ss < 2; ss++) {
            f32x4 rsv = (f32x4){0.f, 0.f, 0.f, 0.f};
#pragma unroll
            for (int nf = 0; nf < 4; nf++) {
#pragma unroll
                for (int r = 0; r < 4; r++) sc[ss][nf][r] = fexp2(sc[ss][nf][r] - mr[ss]);
                rsv += sc[ss][nf];
                pkk[ss][nf][0] = cvt_pk_bf16(sc[ss][nf][0], sc[ss][nf][1]);
                pkk[ss][nf][1] = cvt_pk_bf16(sc[ss][nf][2], sc[ss][nf][3]);
            }
            float rs = (rsv[0] + rsv[1]) + (rsv[2] + rsv[3]);
            rs += __shfl_xor(rs, 16);
            rs += __shfl_xor(rs, 32);
            lr[ss] += rs;
        }

        // A-fragments from own registers (permuted k-slots)
        bf16x8 pa[2][2];
#pragma unroll
        for (int ss = 0; ss < 2; ss++) {
            union { u32 ui[4]; bf16x8 v; } u0, u1;
            u0.ui[0] = pkk[ss][0][0]; u0.ui[1] = pkk[ss][0][1];
            u0.ui[2] = pkk[ss][1][0]; u0.ui[3] = pkk[ss][1][1];
            u1.ui[0] = pkk[ss][2][0]; u1.ui[1] = pkk[ss][2][1];
            u1.ui[2] = pkk[ss][3][0]; u1.ui[3] = pkk[ss][3][1];
            pa[ss][0] = u0.v; pa[ss][1] = u1.v;
        }

        // PV: B-side reads lv columns in the SAME permuted kv order
#pragma unroll
        for (int nf = 0; nf < 4; nf++) {
            union { int2 d[2]; bf16x8 v; } b0, b1;
            b0.d[0] = *(const int2*)&lv[cur][nf * 16 + c][4 * g];
            b0.d[1] = *(const int2*)&lv[cur][nf * 16 + c][16 + 4 * g];
            b1.d[0] = *(const int2*)&lv[cur][nf * 16 + c][32 + 4 * g];
            b1.d[1] = *(const int2*)&lv[cur][nf * 16 + c][48 + 4 * g];
#pragma unroll
            for (int ss = 0; ss < 2; ss++) {
                o[ss][nf] = __builtin_amdgcn_mfma_f32_16x16x32_bf16(pa[ss][0], b0.v, o[ss][nf], 0, 0, 0);
                o[ss][nf] = __builtin_amdgcn_mfma_f32_16x16x32_bf16(pa[ss][1], b1.v, o[ss][nf], 0, 0, 0);
            }
        }

        if (more) WRITET(cur ^ 1);   // stage next tile into alternate buffer
        __syncthreads();             // single barrier per tile (dbuf)
        cur ^= 1;
    }
#undef LOADT
#undef WRITET

    // out[b, n, h*64+hd] = o / l
#pragma unroll
    for (int ss = 0; ss < 2; ss++) {
        float lq[4];
#pragma unroll
        for (int r = 0; r < 4; r++) lq[r] = __shfl(lr[ss], g * 4 + r);
#pragma unroll
        for (int r = 0; r < 4; r++) {
            float inv = 1.f / lq[r];
            int n = q0 + w * 32 + ss * 16 + g * 4 + r;
#pragma unroll
            for (int nf = 0; nf < 4; nf++)
                out[((size_t)(b * N_ + n)) * D_ + h * HD_ + nf * 16 + c] = o[ss][nf][r] * inv;
        }
    }
}

// ---------------- launcher ----------------------------------------------
extern "C" void kernel_launch(void* const* d_in, const int* in_sizes, int n_in,
                              void* d_out, int out_size, void* d_ws, size_t ws_size,
                              hipStream_t stream) {
    const float* x  = (const float*)d_in[0];
    const float* Wq = (const float*)d_in[1];
    const float* bq = (const float*)d_in[2];
    const float* Wk = (const float*)d_in[3];
    const float* bk = (const float*)d_in[4];
    const float* Wv = (const float*)d_in[5];
    const float* bv = (const float*)d_in[6];
    float* out = (float*)d_out;

    char* ws = (char*)d_ws;
    u16* xbf   = (u16*)ws;                      // 16384*768*2 = 25165824 B
    u16* wtall = (u16*)(ws + 25165824);         // 2304*768*2  =  3538944 B
    u16* qbf   = (u16*)(ws + 28704768);         // [B,H,N,64] bf16 (prescaled)
    u16* kbf   = (u16*)(ws + 53870592);         // [B,H,N,64] bf16
    u16* vtbf  = (u16*)(ws + 79036416);         // [B,H,64,N] bf16

    cvt_x_kernel<<<6144, 256, 0, stream>>>(x, xbf);
    dim3 gw(24, 24, 3), bw(32, 8);
    wt_kernel<<<gw, bw, 0, stream>>>(Wq, Wk, Wv, wtall);
    dim3 gg(18, 128);
    qkv2_kernel<<<gg, 256, 0, stream>>>(xbf, wtall, bq, bk, bv, qbf, kbf, vtbf);
    dim3 ga(192, 8);   // bh-major: same-bh q-tiles share an XCD
    attn_kernel<<<ga, 256, 0, stream>>>(qbf, kbf, vtbf, out);
}